// Round 3
// baseline (23789.812 us; speedup 1.0000x reference)
//
#include <hip/hip_runtime.h>
#include <hip/hip_bf16.h>

#define B_SZ 1024
#define T_SZ 128
#define D_SZ 256
#define H_SZ 512
#define NBLK 512

typedef __attribute__((ext_vector_type(8))) short short8;   // bf16x8 frag
typedef __attribute__((ext_vector_type(4))) float f32x4;    // f32 accum frag

__device__ inline void gll16(const void* g, void* l) {
  __builtin_amdgcn_global_load_lds(
      (const __attribute__((address_space(1))) unsigned int*)g,
      (__attribute__((address_space(3))) unsigned int*)l, 16, 0, 0);
}

__device__ inline f32x4 mfma16(short8 a, short8 b, f32x4 c) {
  return __builtin_amdgcn_mfma_f32_16x16x32_bf16(a, b, c, 0, 0, 0);
}

// Stage ROWSx64 bf16 tile into LDS [ROWS][64] ushort, slot-swizzled
// (slot s of row r holds global k-slot s^(r&7)); linear LDS dest for
// global_load_lds + inverse-swizzled SOURCE address (both-sides rule).
template <int ROWS>
__device__ inline void stageT(const __hip_bfloat16* __restrict__ src, int strideElts,
                              int row0, int k0, unsigned short* lds, int tid) {
  int wv = tid >> 6;
  constexpr int CH = ROWS * 8;  // 16B chunks
#pragma unroll
  for (int it = 0; it * 256 < CH; ++it) {
    int wbase = it * 256 + (wv << 6);
    if (wbase < CH) {  // wave-uniform guard
      int chunk = it * 256 + tid;
      int row = chunk >> 3, slot = chunk & 7;
      int ksrc = (slot ^ (row & 7)) << 3;
      const __hip_bfloat16* g = src + (size_t)(row0 + row) * strideElts + (k0 + ksrc);
      unsigned short* l = lds + (size_t)wbase * 8;  // wave-uniform base
      gll16((const void*)g, (void*)l);
    }
  }
}

__device__ inline short8 ldfrag(const unsigned short* lds, int row, int slot) {
  int s = slot ^ (row & 7);
  return *(const short8*)(lds + row * 64 + s * 8);
}

#define TILE_SYNC()                                  \
  do {                                               \
    asm volatile("s_waitcnt vmcnt(0)" ::: "memory"); \
    __builtin_amdgcn_s_barrier();                    \
    __builtin_amdgcn_sched_barrier(0);               \
  } while (0)

// device-scope grid barrier: all NBLK blocks co-resident (512 blocks,
// launch_bounds(256,2), 24KB LDS -> 2 blocks/CU guaranteed).
__device__ __forceinline__ void gridbar(unsigned* cnt, unsigned* gen) {
  __syncthreads();
  if (threadIdx.x == 0) {
    __threadfence();  // agent-scope release of this block's stores
    unsigned g = __hip_atomic_load(gen, __ATOMIC_RELAXED, __HIP_MEMORY_SCOPE_AGENT);
    unsigned a = __hip_atomic_fetch_add(cnt, 1u, __ATOMIC_ACQ_REL, __HIP_MEMORY_SCOPE_AGENT);
    if (a == NBLK - 1) {
      __hip_atomic_store(cnt, 0u, __ATOMIC_RELAXED, __HIP_MEMORY_SCOPE_AGENT);
      __hip_atomic_fetch_add(gen, 1u, __ATOMIC_RELEASE, __HIP_MEMORY_SCOPE_AGENT);
    } else {
      while (__hip_atomic_load(gen, __ATOMIC_RELAXED, __HIP_MEMORY_SCOPE_AGENT) == g)
        __builtin_amdgcn_s_sleep(1);
      __threadfence();  // acquire: invalidate stale cached lines
    }
  }
  __syncthreads();
}

__global__ __launch_bounds__(256, 2) void k_fused(
    const float* __restrict__ x, const float* __restrict__ xtime,
    const __hip_bfloat16* __restrict__ W1t, const float* __restrict__ b1,
    const __hip_bfloat16* __restrict__ W2t, const float* __restrict__ b2,
    const __hip_bfloat16* __restrict__ Wzrt, const float* __restrict__ bz,
    const float* __restrict__ br, const __hip_bfloat16* __restrict__ Wnt,
    const float* __restrict__ bn, float* __restrict__ hf, float* __restrict__ hstdf,
    float* __restrict__ hodef, float* __restrict__ zf,
    __hip_bfloat16* __restrict__ hbf, __hip_bfloat16* __restrict__ Ubf,
    __hip_bfloat16* __restrict__ hodeb, __hip_bfloat16* __restrict__ hstdb,
    __hip_bfloat16* __restrict__ A4, __hip_bfloat16* __restrict__ xstep,
    unsigned* __restrict__ bar) {
  __shared__ __align__(16) unsigned short lA[2][32 * 64];
  __shared__ __align__(16) unsigned short lB[2][64 * 64];
  int tid = threadIdx.x, lane = tid & 63, wv = tid >> 6;
  int b = blockIdx.x;
  int lr = lane & 15, lg = lane >> 4;
  // P1/P2: 16x64 tiles, 64 m x 8 n (n in low bits -> per-XCD weight-col reuse)
  int m0a = (b >> 3) << 4, n0a = (b & 7) << 6;
  // P3/P4: 32x64 tiles, 32 m x 16 n
  int m0b = (b >> 4) << 5, n0b = (b & 15) << 6;
  int wr = wv & 1, wc = wv >> 1;  // P3/P4 wave roles: m-sub 16, n-sub 32
  unsigned* cnt = bar;
  unsigned* gen = bar + 32;  // separate cache lines

  for (int t = 0; t < T_SZ; ++t) {
    // ============ P1: U = tanh(h @ W1 + b1) ============
    {
      f32x4 acc = {};
      stageT<16>(hbf, H_SZ, m0a, 0, lA[0], tid);
      stageT<64>(W1t, H_SZ, n0a, 0, lB[0], tid);
      int cur = 0;
      for (int kt = 0; kt < 8; ++kt) {
        TILE_SYNC();
        if (kt + 1 < 8) {
          stageT<16>(hbf, H_SZ, m0a, (kt + 1) << 6, lA[cur ^ 1], tid);
          stageT<64>(W1t, H_SZ, n0a, (kt + 1) << 6, lB[cur ^ 1], tid);
        }
#pragma unroll
        for (int kk = 0; kk < 2; ++kk) {
          short8 bfr = ldfrag(lB[cur], (wv << 4) + lr, (kk << 2) + lg);
          short8 afr = ldfrag(lA[cur], lr, (kk << 2) + lg);
          acc = mfma16(afr, bfr, acc);
        }
        cur ^= 1;
      }
      int col = n0a + (wv << 4) + lr;
      float bi = b1[col];
      int r0 = m0a + (lg << 2);
#pragma unroll
      for (int r = 0; r < 4; ++r)
        Ubf[(size_t)(r0 + r) * H_SZ + col] = __float2bfloat16(tanhf(acc[r] + bi));
    }
    gridbar(cnt, gen);
    // ============ P2: h_ode = h + dt*(U @ W2 + b2); x slice -> bf16 ============
    {
      f32x4 acc = {};
      stageT<16>(Ubf, H_SZ, m0a, 0, lA[0], tid);
      stageT<64>(W2t, H_SZ, n0a, 0, lB[0], tid);
      int cur = 0;
      for (int kt = 0; kt < 8; ++kt) {
        TILE_SYNC();
        if (kt + 1 < 8) {
          stageT<16>(Ubf, H_SZ, m0a, (kt + 1) << 6, lA[cur ^ 1], tid);
          stageT<64>(W2t, H_SZ, n0a, (kt + 1) << 6, lB[cur ^ 1], tid);
        }
#pragma unroll
        for (int kk = 0; kk < 2; ++kk) {
          short8 bfr = ldfrag(lB[cur], (wv << 4) + lr, (kk << 2) + lg);
          short8 afr = ldfrag(lA[cur], lr, (kk << 2) + lg);
          acc = mfma16(afr, bfr, acc);
        }
        cur ^= 1;
      }
      float dt = (t == 0) ? 0.01f : (xtime[t] - xtime[t - 1]);
      int col = n0a + (wv << 4) + lr;
      float bi = b2[col];
      int r0 = m0a + (lg << 2);
#pragma unroll
      for (int r = 0; r < 4; ++r) {
        size_t ix = (size_t)(r0 + r) * H_SZ + col;
        float v = hf[ix] + dt * (acc[r] + bi);
        hodef[ix] = v;
        hodeb[ix] = __float2bfloat16(v);
      }
      if ((b & 7) == 0) {  // convert this step's x slice, rows m0a..m0a+15
#pragma unroll
        for (int it = 0; it < 16; ++it) {
          int row = m0a + it;
          float xv = x[((size_t)row * T_SZ + t) * D_SZ + tid];
          xstep[(size_t)row * D_SZ + tid] = __float2bfloat16(xv);
        }
      }
    }
    gridbar(cnt, gen);
    // ============ P3: z|r = sigmoid(cat @ [Wz|Wr] + b); build A4 ============
    {
      f32x4 acc[2] = {};
      stageT<32>(hodeb, H_SZ, m0b, 0, lA[0], tid);
      stageT<64>(Wzrt, 1280, n0b, 0, lB[0], tid);
      int cur = 0;
      for (int kt = 0; kt < 20; ++kt) {
        TILE_SYNC();
        if (kt + 1 < 20) {
          int ke = (kt + 1) << 6;
          if (ke < 512)       stageT<32>(hodeb, H_SZ, m0b, ke, lA[cur ^ 1], tid);
          else if (ke < 1024) stageT<32>(hstdb, H_SZ, m0b, ke - 512, lA[cur ^ 1], tid);
          else                stageT<32>(xstep, D_SZ, m0b, ke - 1024, lA[cur ^ 1], tid);
          stageT<64>(Wzrt, 1280, n0b, ke, lB[cur ^ 1], tid);
        }
#pragma unroll
        for (int kk = 0; kk < 2; ++kk) {
          short8 afr = ldfrag(lA[cur], (wr << 4) + lr, (kk << 2) + lg);
#pragma unroll
          for (int n = 0; n < 2; ++n) {
            short8 bfr = ldfrag(lB[cur], (wc << 5) + (n << 4) + lr, (kk << 2) + lg);
            acc[n] = mfma16(afr, bfr, acc[n]);
          }
        }
        cur ^= 1;
      }
      bool isz = (n0b < 512);
#pragma unroll
      for (int n = 0; n < 2; ++n) {
        int cg = n0b + (wc << 5) + (n << 4) + lr;  // 0..1023
        int r0 = m0b + (wr << 4) + (lg << 2);
        float bi = isz ? bz[cg] : br[cg - 512];
#pragma unroll
        for (int r = 0; r < 4; ++r) {
          int row = r0 + r;
          float g = 1.f / (1.f + expf(-(acc[n][r] + bi)));
          if (isz) {
            zf[(size_t)row * H_SZ + cg] = g;
          } else {
            int j = cg - 512;
            size_t ix = (size_t)row * H_SZ + j;
            A4[(size_t)row * 1024 + j]       = __float2bfloat16(hodef[ix] * g);
            A4[(size_t)row * 1024 + 512 + j] = __float2bfloat16(hstdf[ix] * g);
          }
        }
      }
    }
    gridbar(cnt, gen);
    // ============ P4: n = cat_r @ Wn + bn ; GRU update ============
    {
      f32x4 acc[2] = {};
      stageT<32>(A4, 1024, m0b, 0, lA[0], tid);
      stageT<64>(Wnt, 1280, n0b, 0, lB[0], tid);
      int cur = 0;
      for (int kt = 0; kt < 20; ++kt) {
        TILE_SYNC();
        if (kt + 1 < 20) {
          int ke = (kt + 1) << 6;
          if (ke < 1024) stageT<32>(A4, 1024, m0b, ke, lA[cur ^ 1], tid);
          else           stageT<32>(xstep, D_SZ, m0b, ke - 1024, lA[cur ^ 1], tid);
          stageT<64>(Wnt, 1280, n0b, ke, lB[cur ^ 1], tid);
        }
#pragma unroll
        for (int kk = 0; kk < 2; ++kk) {
          short8 afr = ldfrag(lA[cur], (wr << 4) + lr, (kk << 2) + lg);
#pragma unroll
          for (int n = 0; n < 2; ++n) {
            short8 bfr = ldfrag(lB[cur], (wc << 5) + (n << 4) + lr, (kk << 2) + lg);
            acc[n] = mfma16(afr, bfr, acc[n]);
          }
        }
        cur ^= 1;
      }
      bool ismean = (n0b < 512);
#pragma unroll
      for (int n = 0; n < 2; ++n) {
        int c = n0b + (wc << 5) + (n << 4) + lr;  // 0..1023
        int r0 = m0b + (wr << 4) + (lg << 2);
        float bi = bn[c];
#pragma unroll
        for (int r = 0; r < 4; ++r) {
          int row = r0 + r;
          if (ismean) {
            size_t ix = (size_t)row * H_SZ + c;
            float nm = acc[n][r] + bi;
            float z = zf[ix], ho = hodef[ix];
            float hn = (1.f - z) * nm + z * ho;
            hf[ix] = hn;
            hbf[ix] = __float2bfloat16(hn);
          } else {
            int j = c - 512;
            size_t ix = (size_t)row * H_SZ + j;
            float ns = fabsf(acc[n][r] + bi);
            float z = zf[ix], hs = hstdf[ix];
            float sn = fabsf((1.f - z) * ns + z * hs);
            hstdf[ix] = sn;
            hstdb[ix] = __float2bfloat16(sn);
          }
        }
      }
    }
    gridbar(cnt, gen);
  }
}

// =============== prep: W[k][n] f32  ->  Wt[n][k] bf16 =====================
__global__ void k_wt(const float* __restrict__ W, __hip_bfloat16* __restrict__ Wt,
                     int K, int N, int ld) {
  size_t i = (size_t)blockIdx.x * 256 + threadIdx.x;
  if (i >= (size_t)K * N) return;
  int n = (int)(i / K), k = (int)(i % K);
  Wt[(size_t)n * ld + k] = __float2bfloat16(W[(size_t)k * N + n]);
}

extern "C" void kernel_launch(void* const* d_in, const int* in_sizes, int n_in,
                              void* d_out, int out_size, void* d_ws, size_t ws_size,
                              hipStream_t stream) {
  const float* x     = (const float*)d_in[0];
  const float* xtime = (const float*)d_in[1];
  const float* W1    = (const float*)d_in[2];
  const float* b1    = (const float*)d_in[3];
  const float* W2    = (const float*)d_in[4];
  const float* b2    = (const float*)d_in[5];
  const float* Wz    = (const float*)d_in[6];
  const float* bz    = (const float*)d_in[7];
  const float* Wr    = (const float*)d_in[8];
  const float* br    = (const float*)d_in[9];
  const float* Wn    = (const float*)d_in[10];
  const float* bn    = (const float*)d_in[11];

  char* p = (char*)d_ws;
  __hip_bfloat16* W1t   = (__hip_bfloat16*)(p + 0);         //  512x512
  __hip_bfloat16* W2t   = (__hip_bfloat16*)(p + 524288);    //  512x512
  __hip_bfloat16* Wzrt  = (__hip_bfloat16*)(p + 1048576);   // 1024x1280
  __hip_bfloat16* Wnt   = (__hip_bfloat16*)(p + 3670016);   // 1024x1280
  float*          hf    = (float*)(p + 6291456);            // 1024x512 state
  float*          hstdf = (float*)(p + 8388608);            // 1024x512 state
  float*          hodef = (float*)(p + 10485760);
  float*          zf    = (float*)(p + 12582912);
  __hip_bfloat16* hbf   = (__hip_bfloat16*)(p + 14680064);
  __hip_bfloat16* Ubf   = (__hip_bfloat16*)(p + 15728640);
  __hip_bfloat16* hodeb = (__hip_bfloat16*)(p + 16777216);
  __hip_bfloat16* hstdb = (__hip_bfloat16*)(p + 17825792);
  __hip_bfloat16* A4    = (__hip_bfloat16*)(p + 18874368);  // 1024x1024
  __hip_bfloat16* xstep = (__hip_bfloat16*)(p + 20971520);  // 1024x256
  unsigned*       bar   = (unsigned*)(p + 21495808);        // grid barrier state

  // zero recurrent state + barrier (harness does not re-poison between replays)
  hipMemsetAsync(hf, 0, 2097152, stream);
  hipMemsetAsync(hstdf, 0, 2097152, stream);
  hipMemsetAsync(hbf, 0, 1048576, stream);
  hipMemsetAsync(hstdb, 0, 1048576, stream);
  hipMemsetAsync(bar, 0, 256, stream);

  // weights -> bf16, transposed to [N][K]
  k_wt<<<(512 * 512 + 255) / 256, 256, 0, stream>>>(W1, W1t, 512, 512, 512);
  k_wt<<<(512 * 512 + 255) / 256, 256, 0, stream>>>(W2, W2t, 512, 512, 512);
  k_wt<<<(1280 * 512 + 255) / 256, 256, 0, stream>>>(Wz, Wzrt, 1280, 512, 1280);
  k_wt<<<(1280 * 512 + 255) / 256, 256, 0, stream>>>(Wr, Wzrt + (size_t)512 * 1280, 1280, 512, 1280);
  k_wt<<<(1280 * 1024 + 255) / 256, 256, 0, stream>>>(Wn, Wnt, 1280, 1024, 1280);

  // one persistent kernel for all 128 steps (512 co-resident blocks)
  k_fused<<<NBLK, 256, 0, stream>>>(x, xtime, W1t, b1, W2t, b2, Wzrt, bz, br,
                                    Wnt, bn, hf, hstdf, hodef, zf, hbf, Ubf,
                                    hodeb, hstdb, A4, xstep, bar);

  hipMemcpyAsync(d_out, hf, 2097152, hipMemcpyDeviceToDevice, stream);
  hipMemcpyAsync((char*)d_out + 2097152, hstdf, 2097152, hipMemcpyDeviceToDevice, stream);
}